// Round 3
// baseline (6217.534 us; speedup 1.0000x reference)
//
#include <hip/hip_runtime.h>

typedef unsigned int u32;
typedef unsigned long long u64;
typedef float    f4  __attribute__((ext_vector_type(4)));
typedef _Float16 h2v __attribute__((ext_vector_type(2)));

#define B_ 32
#define T_ 2048
#define D_ 256
#define H_ 256
#define G_ 512  // 2H

// Precision: GRU recurrence amplifies per-step error ~6e4x over T=2048
// (fp16 loop: absmax 0.316; fp32 loop: 0.0039). Recurrent path stays fp32.
// Capacity: 768KB fp32 recurrent weights > one CU's 512KB RF -> WG pair per
// weight image (K-split GEMV1, output-split GEMV2, ONE exchange per step).
// Round-6 (latency hiding): step = ~6100cy, of which RT ~2400cy + serial
// sections ~3200cy, VALU only ~500cy. Weights are batch-invariant, so each
// WG pair now serves TWO batch elements (nb=2): batch 0's exchange RT hides
// under batch 1's GEMV1/publish, and barriers + serial tail (now 64-wide)
// amortize over 2 batch-steps. 16 pairs x 2 batches = 32 batch elements.
//  - h-publish moved into the tail: the thread that computes h_new publishes
//    it immediately for step t+1 (tag t+2, parity (t+1)&1) from registers.
//    Prologue publishes h=0 (tag 1, parity 0) before the loop.
//  - payload [16][2 j][2 parity][2 k][512] u64 = 524288 B: same footprint
//    as round 2 (proven to fit the workspace).
//  - deadlock audit (parity dbuf): overwrite of any slot at step t+2 follows
//    my B(t+1)-poll success -> partner's A(t+1) publish -> partner's H(t)
//    barrier -> partner consumed step-t data. Holds for partial AND h slots.
//  - tagged 8B relaxed agent atomics (value<<32 | tag); 0xAA poison never
//    matches tag <= 2050; stale tags from a previous timing iteration carry
//    identical (deterministic) values -> benign.

__device__ __forceinline__ float fsigmoid(float x){
  return 1.f / (1.f + __expf(-x));
}
__device__ __forceinline__ float ftanh(float x){
  float a = fabsf(x);
  float e = __expf(2.f * a);
  float t = 1.f - 2.f / (e + 1.f);
  return copysignf(t, x);
}
__device__ __forceinline__ u32 pack2(float a, float b){
  h2v p = {(_Float16)a, (_Float16)b};
  return __builtin_bit_cast(u32, p);
}
__device__ __forceinline__ u64 tag_pack(float v, u32 tag){
  return ((u64)__builtin_bit_cast(u32, v) << 32) | (u64)tag;
}
__device__ __forceinline__ float tag_val(u64 x){
  return __builtin_bit_cast(float, (u32)(x >> 32));
}

// ---------------------------------------------------------------------------
// Phase 0: pack recurrent weights (fp32 bit-exact) into gru_pair's register
// layout. WG image j:
//   GEMV1 (K-split rows 128j..128j+128 of Wg_h, col = tid):
//     r in [0,128):   -> Wg[(256 + 128j + r)][tid]
//   GEMV2 (output-split cols 128j..128j+128 of Wc_h, full K):
//     thread t: w=t>>6, l=t&63, g=w>>2, a=w&3, lh=(l>>5)&1
//     c2 = 32a + (l&31), kr = 128g + 64lh + rr
//     r in [128,192): rr=r-128 -> Wc[(256 + kr)][128j + c2]
// Linear: wgp[j*98304 + r*512 + t]  (coalesced in gru_pair's preamble).
// ---------------------------------------------------------------------------
__global__ __launch_bounds__(256) void pack_w(
    const float* __restrict__ Wg, const float* __restrict__ Wc,
    float* __restrict__ wgp)
{
  int idx = blockIdx.x * 256 + threadIdx.x;          // [0, 196608)
  int j  = idx / 98304;
  int r2 = idx - j * 98304;
  int r = r2 >> 9;
  int t = r2 & 511;
  float v;
  if (r < 128){
    v = Wg[(size_t)(256 + 128*j + r) * G_ + t];
  } else {
    int rr = r - 128;
    int w = t >> 6, l = t & 63;
    int g = w >> 2, a = w & 3, lh = (l >> 5) & 1;
    int c2 = 32*a + (l & 31);
    int kr = 128*g + 64*lh + rr;
    v = Wc[(size_t)(256 + kr) * H_ + 128*j + c2];
  }
  wgp[idx] = v;
}

// ---------------------------------------------------------------------------
// Phase 1: Gx = X @ Wg[:256,:] + bg   [65536 x 512] fp32
//          Cx = X @ Wc[:256,:] + bc   [65536 x 256] fp32
// ---------------------------------------------------------------------------
__global__ __launch_bounds__(256) void input_proj(
    const float* __restrict__ X, const float* __restrict__ Wg, const float* __restrict__ bg,
    const float* __restrict__ Wc, const float* __restrict__ bc,
    float* __restrict__ gx, float* __restrict__ cx)
{
  __shared__ __align__(16) float At[16][64];   // [k][m]
  __shared__ __align__(16) float Bt[16][64];   // [k][n]
  const int t  = threadIdx.x;
  const int m0 = blockIdx.x*64, n0 = blockIdx.y*64;
  const int tm = (t & 15)*4, tn = (t >> 4)*4;
  const int lm = t >> 2,  lk = (t & 3)*4;
  const int bk = t >> 4,  bn = (t & 15)*4;
  const float* bsrc; int bld;
  if (n0 < G_) { bsrc = Wg + n0; bld = G_; } else { bsrc = Wc + (n0 - G_); bld = H_; }
  float acc[4][4] = {};
  for (int kc = 0; kc < D_; kc += 16){
    __syncthreads();
    f4 a4 = *(const f4*)&X[(size_t)(m0+lm)*D_ + kc + lk];
    f4 b4 = *(const f4*)&bsrc[(size_t)(kc+bk)*bld + bn];
    At[lk+0][lm] = a4.x; At[lk+1][lm] = a4.y; At[lk+2][lm] = a4.z; At[lk+3][lm] = a4.w;
    *(f4*)&Bt[bk][bn] = b4;
    __syncthreads();
#pragma unroll
    for (int k = 0; k < 16; ++k){
      f4 av = *(const f4*)&At[k][tm];
      f4 bv = *(const f4*)&Bt[k][tn];
#pragma unroll
      for (int i = 0; i < 4; ++i){
        acc[i][0] = fmaf(av[i], bv[0], acc[i][0]);
        acc[i][1] = fmaf(av[i], bv[1], acc[i][1]);
        acc[i][2] = fmaf(av[i], bv[2], acc[i][2]);
        acc[i][3] = fmaf(av[i], bv[3], acc[i][3]);
      }
    }
  }
  if (n0 < G_){
    f4 bb = { bg[n0+tn], bg[n0+tn+1], bg[n0+tn+2], bg[n0+tn+3] };
#pragma unroll
    for (int i = 0; i < 4; ++i){
      f4 v = { acc[i][0]+bb.x, acc[i][1]+bb.y, acc[i][2]+bb.z, acc[i][3]+bb.w };
      *(f4*)&gx[(size_t)(m0+tm+i)*G_ + n0 + tn] = v;
    }
  } else {
    int nn = n0 - G_;
    f4 bb = { bc[nn+tn], bc[nn+tn+1], bc[nn+tn+2], bc[nn+tn+3] };
#pragma unroll
    for (int i = 0; i < 4; ++i){
      f4 v = { acc[i][0]+bb.x, acc[i][1]+bb.y, acc[i][2]+bb.z, acc[i][3]+bb.w };
      *(f4*)&cx[(size_t)(m0+tm+i)*H_ + nn + tn] = v;
    }
  }
}

// ---------------------------------------------------------------------------
// Phase 2: sequential GRU, fp32-exact, 512 thr/WG, WG pair per weight image,
// TWO batch elements per pair (blockIdx = j*16 + p; batches 2p, 2p+1).
// Weights pinned in VGPRs (waves_per_eu(2,2) => 256-reg budget; asm pin
// defeats remat). ONE cross-WG exchange per batch-step via tagged 8B relaxed
// agent atomics, double-buffered by step parity; 3 barriers per step-iter
// (covering both batches).
//
// Payload entry map (sender j, per batch k, 512 u64):
//   [0,256)   : raw GEMV1 partial for r-col e           (thread e)
//   [256,384) : raw GEMV1 partial for PARTNER's u-half
//   [384,512) : own h-half h[128j + i] for THIS step    (published by the
//               tail of the previous step / prologue)
// ---------------------------------------------------------------------------
__global__ __launch_bounds__(512)
__attribute__((amdgpu_waves_per_eu(2, 2)))
void gru_pair(
    const float* __restrict__ gx,      // [B][T][512] fp32, bias baked
    const float* __restrict__ cx,      // [B][T][256] fp32, bias baked
    const float* __restrict__ wgp,     // packed fp32 recurrent weights
    u64* __restrict__ pay,             // [16][2 j][2 par][2 k][512] tagged
    unsigned short* __restrict__ hseq) // [B][T][256] fp16 (output path only)
{
  __shared__ __align__(16) float h32[2][128];     // own h-half, per batch
  __shared__ __align__(16) float rh[2][256];      // r .* h (full), per batch
  __shared__ __align__(16) float ug[2][128];      // own u-half, per batch
  __shared__ __align__(16) float part2[2][4][128];

  const int tid = threadIdx.x;
  const int w = tid >> 6, l = tid & 63;
  const int p = blockIdx.x & 15;
  const int j = blockIdx.x >> 4;

  // roles (all wave-uniform)
  const bool is_r   = (tid < 256);
  const int  su     = (tid - 256) >> 7;             // valid for tid>=256
  const bool is_myu = (tid >= 256) && (su == j);    // owns own u-half col
  const int  i_u    = tid - 256 - 128*j;            // my-u local index
  const int  i_pu   = tid - 256 - 128*(1-j);        // partner-u local index
  const bool h_from_pay = is_r && (((tid >> 7) & 1) != j);
  const int  hcol   = tid & 127;

  // GEMV2 geometry
  const int g2 = w >> 2, aw = w & 3, lh = (l >> 5) & 1;
  const int c2 = 32*aw + (l & 31);
  const int q2 = 2*g2 + lh;
  const int kb = 128*g2 + 64*lh;

  // ---- weight preamble: 192 fp32/thread into VGPRs (coalesced) ----
  const float* wbase = wgp + (size_t)j * 98304;
  float wg[128];
#pragma unroll
  for (int r = 0; r < 128; ++r) wg[r] = wbase[(size_t)r*512 + tid];
  float wc[64];
#pragma unroll
  for (int r = 0; r < 64; ++r) wc[r] = wbase[(size_t)(128+r)*512 + tid];
  // opaque pin: values become asm-defined -> cannot be remat-sunk into the loop
#pragma unroll
  for (int r = 0; r < 128; ++r) asm volatile("" : "+v"(wg[r]));
#pragma unroll
  for (int r = 0; r < 64; ++r) asm volatile("" : "+v"(wc[r]));

  if (tid < 256) h32[tid >> 7][tid & 127] = 0.f;
  __syncthreads();

  const float* gxb0 = gx + (size_t)(2*p + 0) * T_ * G_;
  const float* gxb1 = gx + (size_t)(2*p + 1) * T_ * G_;
  const float* cxk  = cx + (size_t)(2*p + ((tid >> 5) & 1)) * T_ * H_ + 128*j;
  unsigned short* hbk = hseq + (size_t)(2*p + ((tid >> 5) & 1)) * T_ * H_ + 128*j;

  // payload bases: [pairImg][par][k][512]; par stride 1024, k stride 512
  u64* own_base = pay + (size_t)(p*2 + j)     * 2048;
  u64* oth_base = pay + (size_t)(p*2 + (1-j)) * 2048;

  // prologue: publish h(t=0)=0, tag 1, parity 0, both batches
  if (tid < 128){
    __hip_atomic_store(own_base +   0 + 384 + tid, tag_pack(0.f, 1u),
                       __ATOMIC_RELAXED, __HIP_MEMORY_SCOPE_AGENT);
    __hip_atomic_store(own_base + 512 + 384 + tid, tag_pack(0.f, 1u),
                       __ATOMIC_RELAXED, __HIP_MEMORY_SCOPE_AGENT);
  }

  for (int t = 0; t < T_; ++t){
    const u32 tag = (u32)(t + 1);
    u64* ownp = own_base + (size_t)(t & 1) * 1024;
    u64* othp = oth_base + (size_t)(t & 1) * 1024;

    // prefetch gx (both batches) + cx (tail threads' own batch)
    float g0 = gxb0[(size_t)t * G_ + tid];
    float g1 = gxb1[(size_t)t * G_ + tid];
    f4 c4 = {0.f, 0.f, 0.f, 0.f};
    if (tid < 64) c4 = *(const f4*)(cxk + (size_t)t * H_ + 4*(tid & 31));

    // ---- Phase A: GEMV1 x2 (own k-half, own col = tid) + publish ----
    float accs[2];
#pragma unroll
    for (int k = 0; k < 2; ++k){
      float a0 = 0.f, a1 = 0.f, a2 = 0.f, a3 = 0.f;
#pragma unroll
      for (int kc = 0; kc < 128; kc += 16){
        f4 h0 = *(const f4*)&h32[k][kc + 0];
        f4 h1 = *(const f4*)&h32[k][kc + 4];
        f4 h2 = *(const f4*)&h32[k][kc + 8];
        f4 h3 = *(const f4*)&h32[k][kc + 12];
        a0 = fmaf(wg[kc+ 0], h0.x, a0); a1 = fmaf(wg[kc+ 1], h0.y, a1);
        a2 = fmaf(wg[kc+ 2], h0.z, a2); a3 = fmaf(wg[kc+ 3], h0.w, a3);
        a0 = fmaf(wg[kc+ 4], h1.x, a0); a1 = fmaf(wg[kc+ 5], h1.y, a1);
        a2 = fmaf(wg[kc+ 6], h1.z, a2); a3 = fmaf(wg[kc+ 7], h1.w, a3);
        a0 = fmaf(wg[kc+ 8], h2.x, a0); a1 = fmaf(wg[kc+ 9], h2.y, a1);
        a2 = fmaf(wg[kc+10], h2.z, a2); a3 = fmaf(wg[kc+11], h2.w, a3);
        a0 = fmaf(wg[kc+12], h3.x, a0); a1 = fmaf(wg[kc+13], h3.y, a1);
        a2 = fmaf(wg[kc+14], h3.z, a2); a3 = fmaf(wg[kc+15], h3.w, a3);
      }
      accs[k] = (a0 + a1) + (a2 + a3);
      if (is_r)
        __hip_atomic_store(ownp + k*512 + tid, tag_pack(accs[k], tag),
                           __ATOMIC_RELAXED, __HIP_MEMORY_SCOPE_AGENT);
      else if (!is_myu)
        __hip_atomic_store(ownp + k*512 + 256 + i_pu, tag_pack(accs[k], tag),
                           __ATOMIC_RELAXED, __HIP_MEMORY_SCOPE_AGENT);
    }

    // hardening: forbid compiler from moving the publishes below the polls
    asm volatile("" ::: "memory");

    // ---- Phase B: poll + combine (RT of batch 0 hidden under batch 1's A)
#pragma unroll
    for (int k = 0; k < 2; ++k){
      const float g = k ? g1 : g0;
      u64* othk = othp + k*512;
      if (is_r){
        if (h_from_pay){
          u64 vp, vh;
          for (;;){
            vp = __hip_atomic_load(othk + tid,        __ATOMIC_RELAXED, __HIP_MEMORY_SCOPE_AGENT);
            vh = __hip_atomic_load(othk + 384 + hcol, __ATOMIC_RELAXED, __HIP_MEMORY_SCOPE_AGENT);
            if (((u32)vp == tag) & ((u32)vh == tag)) break;
          }
          float pre = accs[k] + tag_val(vp) + g;
          rh[k][tid] = fsigmoid(pre) * tag_val(vh);
        } else {
          u64 vp;
          for (;;){
            vp = __hip_atomic_load(othk + tid, __ATOMIC_RELAXED, __HIP_MEMORY_SCOPE_AGENT);
            if ((u32)vp == tag) break;
          }
          float pre = accs[k] + tag_val(vp) + g;
          rh[k][tid] = fsigmoid(pre) * h32[k][hcol];
        }
      } else if (is_myu){
        u64 vp;
        for (;;){
          vp = __hip_atomic_load(othk + 256 + i_u, __ATOMIC_RELAXED, __HIP_MEMORY_SCOPE_AGENT);
          if ((u32)vp == tag) break;
        }
        float pre = accs[k] + tag_val(vp) + g;
        ug[k][i_u] = fsigmoid(pre);
      }
    }
    __syncthreads();                                   // (D) rh/ug ready

    // ---- Phase C: GEMV2 x2 (full K=256 over rh, own output col c2) ----
#pragma unroll
    for (int k = 0; k < 2; ++k){
      float s0 = 0.f, s1 = 0.f, s2 = 0.f, s3 = 0.f;
#pragma unroll
      for (int kc = 0; kc < 64; kc += 16){
        f4 r0 = *(const f4*)&rh[k][kb + kc + 0];
        f4 r1 = *(const f4*)&rh[k][kb + kc + 4];
        f4 r2 = *(const f4*)&rh[k][kb + kc + 8];
        f4 r3 = *(const f4*)&rh[k][kb + kc + 12];
        s0 = fmaf(wc[kc+ 0], r0.x, s0); s1 = fmaf(wc[kc+ 1], r0.y, s1);
        s2 = fmaf(wc[kc+ 2], r0.z, s2); s3 = fmaf(wc[kc+ 3], r0.w, s3);
        s0 = fmaf(wc[kc+ 4], r1.x, s0); s1 = fmaf(wc[kc+ 5], r1.y, s1);
        s2 = fmaf(wc[kc+ 6], r1.z, s2); s3 = fmaf(wc[kc+ 7], r1.w, s3);
        s0 = fmaf(wc[kc+ 8], r2.x, s0); s1 = fmaf(wc[kc+ 9], r2.y, s1);
        s2 = fmaf(wc[kc+10], r2.z, s2); s3 = fmaf(wc[kc+11], r2.w, s3);
        s0 = fmaf(wc[kc+12], r3.x, s0); s1 = fmaf(wc[kc+13], r3.y, s1);
        s2 = fmaf(wc[kc+14], r3.z, s2); s3 = fmaf(wc[kc+15], r3.w, s3);
      }
      part2[k][q2][c2] = (s0 + s1) + (s2 + s3);
    }
    __syncthreads();                                   // (E) part2 ready

    // ---- Phase D: tail, 64 threads (2 batches x 32), publish h(t+1) ----
    if (tid < 64){
      const int k  = (tid >> 5) & 1;
      const int ii = tid & 31;
      f4 s = *(const f4*)&part2[k][0][4*ii];
      s += *(const f4*)&part2[k][1][4*ii];
      s += *(const f4*)&part2[k][2][4*ii];
      s += *(const f4*)&part2[k][3][4*ii];
      s += c4;
      f4 cv;
      cv.x = ftanh(s.x); cv.y = ftanh(s.y);
      cv.z = ftanh(s.z); cv.w = ftanh(s.w);
      f4 uv = *(const f4*)&ug[k][4*ii];
      f4 hv = *(const f4*)&h32[k][4*ii];
      f4 one = {1.f, 1.f, 1.f, 1.f};
      f4 hn = uv*hv + (one - uv)*cv;
      *(f4*)&h32[k][4*ii] = hn;
      // publish h for step t+1 (tag t+2, parity (t+1)&1) straight from regs
      u64* ow = own_base + (size_t)((t+1) & 1) * 1024 + (size_t)k*512 + 384 + 4*ii;
      __hip_atomic_store(ow + 0, tag_pack(hn.x, tag + 1), __ATOMIC_RELAXED, __HIP_MEMORY_SCOPE_AGENT);
      __hip_atomic_store(ow + 1, tag_pack(hn.y, tag + 1), __ATOMIC_RELAXED, __HIP_MEMORY_SCOPE_AGENT);
      __hip_atomic_store(ow + 2, tag_pack(hn.z, tag + 1), __ATOMIC_RELAXED, __HIP_MEMORY_SCOPE_AGENT);
      __hip_atomic_store(ow + 3, tag_pack(hn.w, tag + 1), __ATOMIC_RELAXED, __HIP_MEMORY_SCOPE_AGENT);
      uint2 pk;
      pk.x = pack2(hn.x, hn.y);
      pk.y = pack2(hn.z, hn.w);
      *(uint2*)(hbk + (size_t)t*H_ + 4*ii) = pk;
    }
    __syncthreads();                                   // (H) h ready for t+1
  }
}

// ---------------------------------------------------------------------------
// Phase 3: out = sigmoid(Hseq @ Wp + bp); fp16 A (output path only), fp32 out.
// ---------------------------------------------------------------------------
__global__ __launch_bounds__(256) void out_proj(
    const unsigned short* __restrict__ hs, const float* __restrict__ Wp,
    const float* __restrict__ bp, float* __restrict__ out)
{
  __shared__ __align__(16) float At[16][64];
  __shared__ __align__(16) float Bt[16][64];
  const int t  = threadIdx.x;
  const int m0 = blockIdx.x*64, n0 = blockIdx.y*64;
  const int tm = (t & 15)*4, tn = (t >> 4)*4;
  const int lm = t >> 2,  lk = (t & 3)*4;
  const int bk = t >> 4,  bn = (t & 15)*4;
  float acc[4][4] = {};
  for (int kc = 0; kc < H_; kc += 16){
    __syncthreads();
    uint2 a2 = *(const uint2*)(hs + (size_t)(m0+lm)*H_ + kc + lk);
    f4  b4 = *(const f4*)&Wp[(size_t)(kc+bk)*256 + n0 + bn];
    h2v a0 = __builtin_bit_cast(h2v, a2.x), a1 = __builtin_bit_cast(h2v, a2.y);
    At[lk+0][lm] = (float)a0.x; At[lk+1][lm] = (float)a0.y;
    At[lk+2][lm] = (float)a1.x; At[lk+3][lm] = (float)a1.y;
    *(f4*)&Bt[bk][bn] = b4;
    __syncthreads();
#pragma unroll
    for (int k = 0; k < 16; ++k){
      f4 av = *(const f4*)&At[k][tm];
      f4 bv = *(const f4*)&Bt[k][tn];
#pragma unroll
      for (int i = 0; i < 4; ++i){
        acc[i][0] = fmaf(av[i], bv[0], acc[i][0]);
        acc[i][1] = fmaf(av[i], bv[1], acc[i][1]);
        acc[i][2] = fmaf(av[i], bv[2], acc[i][2]);
        acc[i][3] = fmaf(av[i], bv[3], acc[i][3]);
      }
    }
  }
  float b0=bp[n0+tn], b1=bp[n0+tn+1], b2=bp[n0+tn+2], b3=bp[n0+tn+3];
#pragma unroll
  for (int i = 0; i < 4; ++i){
    f4 r;
    r.x = fsigmoid(acc[i][0]+b0); r.y = fsigmoid(acc[i][1]+b1);
    r.z = fsigmoid(acc[i][2]+b2); r.w = fsigmoid(acc[i][3]+b3);
    *(f4*)&out[(size_t)(m0+tm+i)*256 + n0 + tn] = r;
  }
}

// ---------------------------------------------------------------------------
extern "C" void kernel_launch(void* const* d_in, const int* in_sizes, int n_in,
                              void* d_out, int out_size, void* d_ws, size_t ws_size,
                              hipStream_t stream)
{
  const float* x  = (const float*)d_in[0];
  const float* Wg = (const float*)d_in[1];
  const float* bg = (const float*)d_in[2];
  const float* Wc = (const float*)d_in[3];
  const float* bc = (const float*)d_in[4];
  const float* Wp = (const float*)d_in[5];
  const float* bp = (const float*)d_in[6];
  float* out = (float*)d_out;

  char* ws = (char*)d_ws;
  // layout (bytes):
  //   Gx    @ 0         : 32*2048*512*4 = 134217728
  //   Cx    @ 134217728 : 32*2048*256*4 =  67108864
  //   Hs    @ 201326592 : 32*2048*256*2 =  33554432  (fp16)
  //   wgp   @ 234881024 : 196608*4      =    786432
  //   pay   @ 235667456 : 16*2*2*2*512*8 =   524288  (tagged u64, dbuf)
  float* Gx = (float*)(ws);
  float* Cx = (float*)(ws + (size_t)134217728);
  unsigned short* Hs = (unsigned short*)(ws + (size_t)201326592);
  float* wgp = (float*)(ws + (size_t)234881024);
  u64* pay = (u64*)(ws + (size_t)235667456);

  pack_w<<<768, 256, 0, stream>>>(Wg, Wc, wgp);
  input_proj<<<dim3(1024, 12), 256, 0, stream>>>(x, Wg, bg, Wc, bc, Gx, Cx);
  gru_pair<<<32, 512, 0, stream>>>(Gx, Cx, wgp, pay, Hs);
  out_proj<<<dim3(1024, 4), 256, 0, stream>>>(Hs, Wp, bp, out);
}